// Round 13
// baseline (56.291 us; speedup 1.0000x reference)
//
#include <hip/hip_runtime.h>
#include <stdint.h>

#define INPUT_SCALE 0.0078125f   // 2^-7

typedef uint32_t u32x4 __attribute__((ext_vector_type(4)));
typedef uint32_t u32x4a __attribute__((ext_vector_type(4), aligned(8)));

__device__ __forceinline__ u32x4 mqsad(uint64_t s0, uint32_t ref, u32x4 acc) {
#if __has_builtin(__builtin_amdgcn_mqsad_u32_u8)
    return __builtin_amdgcn_mqsad_u32_u8(s0, ref, acc);
#else
    u32x4 d;
    asm("v_mqsad_u32_u8 %0, %1, %2, %3" : "=&v"(d) : "v"(s0), "v"(ref), "v"(acc));
    return d;
#endif
}

__device__ __forceinline__ uint32_t alignb(uint32_t hi, uint32_t lo, int b) {
    return __builtin_amdgcn_alignbyte(hi, lo, b);
}

__device__ __forceinline__ uint32_t qbyte(float x) {
    // round(clip(x*128, -127, 127)) + 128  (rintf = round-half-even, matches jnp.round)
    float v = fminf(fmaxf(x * 128.0f, -127.0f), 127.0f);
    return (uint32_t)((int)rintf(v) + 128);
}

// Planar padded geometry: plane = (n*32+c), row stride 136 B = [4 pad][128][4 pad],
// 130 rows = [1 pad][128][1 pad]. All pad bytes 0x80 (quantized zero, bias +128).
#define ROWB 136
#define PLANEB (130 * ROWB)       // 17680 B
#define ROWU 34
#define PLANEU (130 * ROWU)       // 4420 u32

// ---------------- Kernel A: weight scale + mqsad ref pack ----------------
// wref[(kh*32 + c)*32 + f] = bytes(qw(f,c,kh,0)+128, qw(kh,1)+128, qw(kh,2)+128, 0)
// 4th byte 0 -> masked out by MQSAD (weight bytes are never 0 since qw+128 >= 1).
__global__ __launch_bounds__(1024) void quant_weight(const float* __restrict__ w,
                                                     uint32_t* __restrict__ qwp) {
    __shared__ float red[1024];
    __shared__ float s_inv;
    int tid = threadIdx.x;
    float m = 0.0f;
    for (int i = tid; i < 9216; i += 1024) m = fmaxf(m, fabsf(w[i]));
    red[tid] = m;
    __syncthreads();
    for (int s = 512; s > 0; s >>= 1) {
        if (tid < s) red[tid] = fmaxf(red[tid], red[tid + s]);
        __syncthreads();
    }
    if (tid == 0) {
        float s = fmaxf(red[0] / 127.0f, 1e-8f);
        int e; float fr = frexpf(s, &e);            // s = fr * 2^e, fr in [0.5,1)
        int k = (fr >= 0.70710678118654752f) ? e : e - 1;  // round(log2(s))
        s_inv = exp2f((float)(-k));                 // 1/s_w, exact power of 2
    }
    __syncthreads();
    float inv = s_inv;
    for (int u = tid; u < 3072; u += 1024) {
        int kh = u >> 10;                 // 0..2
        int c = (u >> 5) & 31;
        int f = u & 31;
        uint32_t pk = 0;
        #pragma unroll
        for (int kw = 0; kw < 3; ++kw) {
            float v = w[((f * 32 + c) * 3 + kh) * 3 + kw] * inv;
            v = fminf(fmaxf(v, -127.0f), 127.0f);
            pk |= ((uint32_t)((int)rintf(v) + 128) & 0xFFu) << (8 * kw);
        }
        qwp[(kh * 32 + c) * 32 + f] = pk;   // byte 3 stays 0 -> masked
    }
}

// ---------------- Kernel B: quantize + pack x to planar padded bytes ----------------
// Interior blocks (0..4095): thread -> one u32 (4 width px of one channel row).
// Border blocks (4096..4419): fill pad u32s with 0x80808080.
__global__ __launch_bounds__(512) void quant_pack_x(const float4* __restrict__ x4,
                                                    uint32_t* __restrict__ qxp) {
    int b = blockIdx.x;
    int tid = threadIdx.x;
    if (b < 4096) {
        int t = b * 512 + tid;            // [n:4][c:5][h:7][wq:5]
        int wq = t & 31;
        int h = (t >> 5) & 127;
        int c = (t >> 12) & 31;
        int n = t >> 17;
        float4 v = x4[(((size_t)(n * 32 + c) * 128) + h) * 32 + wq];
        uint32_t pk = qbyte(v.x) | (qbyte(v.y) << 8) | (qbyte(v.z) << 16) | (qbyte(v.w) << 24);
        qxp[(size_t)(n * 32 + c) * PLANEU + (h + 1) * ROWU + 1 + wq] = pk;
    } else {
        int idx = (b - 4096) * 512 + tid;  // 324 border u32 per plane x 512 planes
        int p = idx / 324, k = idx - p * 324;
        int r, cu;
        if (k < 34)       { r = 0;   cu = k; }
        else if (k < 68)  { r = 129; cu = k - 34; }
        else { int j = k - 68; r = 1 + (j >> 1); cu = (j & 1) ? 33 : 0; }
        qxp[(size_t)p * PLANEU + r * ROWU + cu] = 0x80808080u;
    }
}

// ---------------- Kernel C: MQSAD conv ----------------
// 256 blocks x 512 thr. Thread: 8 outputs (one row octet) x 8 filters.
// Per (kh,c): one 16B load (bytes 8o..8o+15 of buffer row h+kh, 8-aligned),
// 3 v_alignbyte -> two 8-byte sliding windows, 16 v_mqsad_u32_u8.
// Weights: fg readfirstlane-uniform -> s_load_dwordx8 per (kh,c).
__global__ __launch_bounds__(512, 4) void adder_conv(const uint32_t* __restrict__ qxp,
                                                     const uint32_t* __restrict__ qwp,
                                                     float* __restrict__ out) {
    int tid = threadIdx.x;
    int b = blockIdx.x;
    int n = b >> 4;                       // image
    int hb = b & 15;                      // row-block of 8
    int fg = __builtin_amdgcn_readfirstlane(tid >> 7);  // filter group 0..3 (wave-uniform)
    int hl = (tid >> 4) & 7;
    int oct = tid & 15;                   // output cols 8*oct .. 8*oct+7
    int h = hb * 8 + hl;

    // buffer row for tap kh is (h + kh); col byte base 8*oct (left pad = 4 B,
    // so reg byte 3 = window start for output col 8*oct).
    const char* base0 = (const char*)qxp + (size_t)(n * 32) * PLANEB + (size_t)h * ROWB + 8 * oct;

    u32x4 accA[8], accB[8];
    #pragma unroll
    for (int f = 0; f < 8; ++f) { accA[f] = (u32x4)0; accB[f] = (u32x4)0; }

    #pragma unroll 1
    for (int kh = 0; kh < 3; ++kh) {
        #pragma unroll 4
        for (int c = 0; c < 32; ++c) {
            u32x4 d = *(const u32x4a*)(base0 + (size_t)c * PLANEB + kh * ROWB);
            uint32_t b0 = alignb(d.y, d.x, 3);    // bytes 3..6
            uint32_t b1 = alignb(d.z, d.y, 3);    // bytes 7..10
            uint32_t b2 = alignb(d.w, d.z, 3);    // bytes 11..14
            uint64_t sA = ((uint64_t)b1 << 32) | b0;   // windows for outputs 0..3
            uint64_t sB = ((uint64_t)b2 << 32) | b1;   // windows for outputs 4..7
            const uint32_t* wt = qwp + (kh * 32 + c) * 32 + fg * 8;  // uniform -> s_load
            #pragma unroll
            for (int f = 0; f < 8; ++f) {
                uint32_t wv = wt[f];
                accA[f] = mqsad(sA, wv, accA[f]);
                accB[f] = mqsad(sB, wv, accB[f]);
            }
        }
    }

    size_t obase = (((size_t)n * 32 + fg * 8) * 16384) + (size_t)h * 128 + 8 * oct;
    #pragma unroll
    for (int f = 0; f < 8; ++f) {
        float4 oA = make_float4(-(float)accA[f].x * INPUT_SCALE,
                                -(float)accA[f].y * INPUT_SCALE,
                                -(float)accA[f].z * INPUT_SCALE,
                                -(float)accA[f].w * INPUT_SCALE);
        float4 oB = make_float4(-(float)accB[f].x * INPUT_SCALE,
                                -(float)accB[f].y * INPUT_SCALE,
                                -(float)accB[f].z * INPUT_SCALE,
                                -(float)accB[f].w * INPUT_SCALE);
        float4* op = (float4*)(out + obase + (size_t)f * 16384);
        op[0] = oA;
        op[1] = oB;
    }
}

extern "C" void kernel_launch(void* const* d_in, const int* in_sizes, int n_in,
                              void* d_out, int out_size, void* d_ws, size_t ws_size,
                              hipStream_t stream) {
    const float* x = (const float*)d_in[0];       // (16,32,128,128)
    const float* w = (const float*)d_in[1];       // (32,32,3,3)
    float* out = (float*)d_out;                   // (16,32,128,128)

    uint32_t* qwp = (uint32_t*)d_ws;                          // 12288 B
    uint32_t* qxp = (uint32_t*)((char*)d_ws + 16384);         // 512 planes * 17680 B = 9.05 MB

    quant_weight<<<1, 1024, 0, stream>>>(w, qwp);
    quant_pack_x<<<4420, 512, 0, stream>>>((const float4*)x, qxp);
    adder_conv<<<256, 512, 0, stream>>>(qxp, qwp, out);
}

// Round 14
// 43.836 us; speedup vs baseline: 1.2841x; 1.2841x over previous
//
#include <hip/hip_runtime.h>
#include <stdint.h>

#define INPUT_SCALE 0.0078125f   // 2^-7

__device__ __forceinline__ uint32_t sadu8(uint32_t a, uint32_t b, uint32_t c) {
#if __has_builtin(__builtin_amdgcn_sad_u8)
    return __builtin_amdgcn_sad_u8(a, b, c);
#else
    uint32_t d;
    asm("v_sad_u8 %0, %1, %2, %3" : "=v"(d) : "v"(a), "v"(b), "v"(c));
    return d;
#endif
}

__device__ __forceinline__ uint32_t qbyte(float x) {
    // round(clip(x*128, -127, 127)) + 128  (rintf = round-half-even, matches jnp.round)
    float v = fminf(fmaxf(x * 128.0f, -127.0f), 127.0f);
    return (uint32_t)((int)rintf(v) + 128);
}

// ---------------- Kernel A: weight scale + pack, 9 blocks ----------------
// Tap-major: u = (t*32 + f)*8 + cg, t = kh*3+kw; one tap = 1 KB contiguous.
// Each block redundantly max-reduces all 9216 weights (deterministic), then
// packs its own 256 u32 slice — kills the 1-block serial head of R11.
__global__ __launch_bounds__(256) void quant_weight(const float* __restrict__ w,
                                                    uint32_t* __restrict__ qwp) {
    __shared__ float red[256];
    __shared__ float s_inv;
    int tid = threadIdx.x;
    float m = 0.0f;
    for (int i = tid; i < 9216; i += 256) m = fmaxf(m, fabsf(w[i]));
    red[tid] = m;
    __syncthreads();
    for (int s = 128; s > 0; s >>= 1) {
        if (tid < s) red[tid] = fmaxf(red[tid], red[tid + s]);
        __syncthreads();
    }
    if (tid == 0) {
        float s = fmaxf(red[0] / 127.0f, 1e-8f);
        int e; float fr = frexpf(s, &e);            // s = fr * 2^e, fr in [0.5,1)
        int k = (fr >= 0.70710678118654752f) ? e : e - 1;  // round(log2(s))
        s_inv = exp2f((float)(-k));                 // 1/s_w, exact power of 2
    }
    __syncthreads();
    float inv = s_inv;
    int u = blockIdx.x * 256 + tid;                 // 9*256 = 2304 exactly
    {
        int t = u >> 8;            // tap 0..8
        int rem = u & 255;
        int f = rem >> 3, cg = rem & 7;
        int kh = t / 3, kw = t - kh * 3;
        uint32_t pk = 0;
        #pragma unroll
        for (int b = 0; b < 4; ++b) {
            int c = cg * 4 + b;
            float v = w[((f * 32 + c) * 3 + kh) * 3 + kw] * inv;
            v = fminf(fmaxf(v, -127.0f), 127.0f);
            pk |= ((uint32_t)((int)rintf(v) + 128) & 0xFFu) << (8 * b);
        }
        qwp[u] = pk;
    }
}

// ---------------- Kernel B: fused quantize + SAD conv ----------------
// Tile 32x8. 256 threads = 128 px-pair slots x 2 filter-halves; thread owns
// 2 outputs (rows r, r+4) x 16 filters. Grid 1024 (16 img x 64 tiles).
// vs R11: SMEM weight requests per output HALVED (36 s_load_dwordx16/output),
// compute-per-lgkm-drain DOUBLED (512 sads/tap = 2048 cy >> ~250 cy drain) —
// affordable occupancy drop 32 -> 16 waves/CU. acc[2][16] + 4 transient uint4
// ~ 60 VGPR, statically indexed; (256,4) = 128-VGPR cap, no spill/demotion.
#define LSTRIDE 12  // u32 per pixel slot (32B data + 16B pad)
__global__ __launch_bounds__(256, 4) void adder_conv_fused(const float* __restrict__ x,
                                                           const uint32_t* __restrict__ qwp,
                                                           float* __restrict__ out) {
    __shared__ __align__(16) uint32_t sx[10 * 34 * LSTRIDE];  // 16320 B
    int tid = threadIdx.x;
    // XCD-contiguous remap: XCD k owns 128 consecutive tiles (2 images).
    int b = ((blockIdx.x & 7) << 7) + (blockIdx.x >> 3);
    int n = b >> 6;                 // image 0..15
    int rem = b & 63;               // tile in image
    int h0 = (rem >> 2) * 8, w0 = (rem & 3) * 32;

    // quantize + pack the 10x34 halo (32 ch -> 8 u32/pixel) into LDS.
    // cg = q/340: lanes sweep consecutive pixels of one channel-group.
    for (int q = tid; q < 2720; q += 256) {          // 2720 = 340 px * 8 cg
        int cg = q / 340;
        int pixel = q - cg * 340;
        int r = pixel / 34, cc = pixel - r * 34;
        int gh = h0 - 1 + r, gw = w0 - 1 + cc;
        uint32_t pk = 0x80808080u;                   // quantized-zero padding
        if ((unsigned)gh < 128u && (unsigned)gw < 128u) {
            const float* base = x + (((size_t)n * 32 + cg * 4) * 128 + gh) * 128 + gw;
            pk = qbyte(base[0])
               | (qbyte(base[16384]) << 8)
               | (qbyte(base[32768]) << 16)
               | (qbyte(base[49152]) << 24);
        }
        sx[pixel * LSTRIDE + cg] = pk;
    }
    __syncthreads();

    int fh = __builtin_amdgcn_readfirstlane(tid >> 7);  // filter half (wave-uniform)
    int p = tid & 127;
    int r = p >> 5;           // row slot 0..3 -> output rows r, r+4
    int c = p & 31;           // col in tile

    uint32_t acc[2][16];
    #pragma unroll
    for (int j = 0; j < 2; ++j)
        #pragma unroll
        for (int f = 0; f < 16; ++f) acc[j][f] = 0u;

    int lb0 = (r * 34 + c) * LSTRIDE;
    int lb1 = ((r + 4) * 34 + c) * LSTRIDE;
    #pragma unroll 1
    for (int kh = 0; kh < 3; ++kh) {
        #pragma unroll 1
        for (int kw = 0; kw < 3; ++kw) {
            int toff = (kh * 34 + kw) * LSTRIDE;
            const uint4* p0 = (const uint4*)(sx + lb0 + toff);
            const uint4* p1 = (const uint4*)(sx + lb1 + toff);
            uint4 a0 = p0[0], a1 = p0[1];            // pixel (r+kh, c+kw)
            uint4 b0 = p1[0], b1 = p1[1];            // pixel (r+4+kh, c+kw)
            const uint32_t* wt = qwp + ((kh * 3 + kw) * 32 + fh * 16) * 8;  // uniform -> s_load
            #pragma unroll
            for (int f = 0; f < 16; ++f) {
                const uint4* wp = (const uint4*)(wt + f * 8);
                uint4 wv0 = wp[0], wv1 = wp[1];
                uint32_t s = acc[0][f];
                s = sadu8(a0.x, wv0.x, s);
                s = sadu8(a0.y, wv0.y, s);
                s = sadu8(a0.z, wv0.z, s);
                s = sadu8(a0.w, wv0.w, s);
                s = sadu8(a1.x, wv1.x, s);
                s = sadu8(a1.y, wv1.y, s);
                s = sadu8(a1.z, wv1.z, s);
                s = sadu8(a1.w, wv1.w, s);
                acc[0][f] = s;
                uint32_t t2 = acc[1][f];
                t2 = sadu8(b0.x, wv0.x, t2);
                t2 = sadu8(b0.y, wv0.y, t2);
                t2 = sadu8(b0.z, wv0.z, t2);
                t2 = sadu8(b0.w, wv0.w, t2);
                t2 = sadu8(b1.x, wv1.x, t2);
                t2 = sadu8(b1.y, wv1.y, t2);
                t2 = sadu8(b1.z, wv1.z, t2);
                t2 = sadu8(b1.w, wv1.w, t2);
                acc[1][f] = t2;
            }
        }
    }

    size_t obase = (((size_t)n * 32 + fh * 16) * 128 + (h0 + r)) * 128 + (w0 + c);
    #pragma unroll
    for (int f = 0; f < 16; ++f) {
        out[obase + (size_t)f * 16384]       = -(float)acc[0][f] * INPUT_SCALE;
        out[obase + (size_t)f * 16384 + 512] = -(float)acc[1][f] * INPUT_SCALE;  // +4 rows
    }
}

extern "C" void kernel_launch(void* const* d_in, const int* in_sizes, int n_in,
                              void* d_out, int out_size, void* d_ws, size_t ws_size,
                              hipStream_t stream) {
    const float* x = (const float*)d_in[0];       // (16,32,128,128)
    const float* w = (const float*)d_in[1];       // (32,32,3,3)
    float* out = (float*)d_out;                   // (16,32,128,128)

    uint32_t* qwp = (uint32_t*)d_ws;              // 9216 B

    quant_weight<<<9, 256, 0, stream>>>(w, qwp);
    adder_conv_fused<<<1024, 256, 0, stream>>>(x, qwp, out);
}

// Round 15
// 41.953 us; speedup vs baseline: 1.3418x; 1.0449x over previous
//
#include <hip/hip_runtime.h>
#include <stdint.h>

#define INPUT_SCALE 0.0078125f   // 2^-7

__device__ __forceinline__ uint32_t sadu8(uint32_t a, uint32_t b, uint32_t c) {
#if __has_builtin(__builtin_amdgcn_sad_u8)
    return __builtin_amdgcn_sad_u8(a, b, c);
#else
    uint32_t d;
    asm("v_sad_u8 %0, %1, %2, %3" : "=v"(d) : "v"(a), "v"(b), "v"(c));
    return d;
#endif
}

__device__ __forceinline__ uint32_t qbyte(float x) {
    // round(clip(x*128, -127, 127)) + 128  (rintf = round-half-even, matches jnp.round)
    float v = fminf(fmaxf(x * 128.0f, -127.0f), 127.0f);
    return (uint32_t)((int)rintf(v) + 128);
}

// ---------------- Kernel A: weight scale + pack, 9 blocks ----------------
// Tap-major: u = (t*32 + f)*8 + cg, t = kh*3+kw; one tap = 1 KB contiguous.
__global__ __launch_bounds__(256) void quant_weight(const float* __restrict__ w,
                                                    uint32_t* __restrict__ qwp) {
    __shared__ float red[256];
    __shared__ float s_inv;
    int tid = threadIdx.x;
    float m = 0.0f;
    for (int i = tid; i < 9216; i += 256) m = fmaxf(m, fabsf(w[i]));
    red[tid] = m;
    __syncthreads();
    for (int s = 128; s > 0; s >>= 1) {
        if (tid < s) red[tid] = fmaxf(red[tid], red[tid + s]);
        __syncthreads();
    }
    if (tid == 0) {
        float s = fmaxf(red[0] / 127.0f, 1e-8f);
        int e; float fr = frexpf(s, &e);            // s = fr * 2^e, fr in [0.5,1)
        int k = (fr >= 0.70710678118654752f) ? e : e - 1;  // round(log2(s))
        s_inv = exp2f((float)(-k));                 // 1/s_w, exact power of 2
    }
    __syncthreads();
    float inv = s_inv;
    int u = blockIdx.x * 256 + tid;                 // 9*256 = 2304 exactly
    {
        int t = u >> 8;            // tap 0..8
        int rem = u & 255;
        int f = rem >> 3, cg = rem & 7;
        int kh = t / 3, kw = t - kh * 3;
        uint32_t pk = 0;
        #pragma unroll
        for (int b = 0; b < 4; ++b) {
            int c = cg * 4 + b;
            float v = w[((f * 32 + c) * 3 + kh) * 3 + kw] * inv;
            v = fminf(fmaxf(v, -127.0f), 127.0f);
            pk |= ((uint32_t)((int)rintf(v) + 128) & 0xFFu) << (8 * b);
        }
        qwp[u] = pk;
    }
}

// ---------------- Kernel B: fused quantize + SAD conv ----------------
// Tile 16(w) x 4(h). 256 threads = 64 px x 4 filter-groups of 8.
// Per tap per WAVE: weights = 8 f x 32 B = 256 B = 64 SGPRs -> ONE s_load
// chunk, ONE lgkm drain (16-filter slices = 128 SGPRs exceeded the SGPR file
// and forced 2-3 chunk+drain cycles per tap in R11/R14).
// Grid 4096 = 16 queued blocks/CU, 8 resident (32 waves/CU): finished blocks
// refill continuously -> staging of later blocks overlaps compute of earlier
// (prior rounds ran exactly 4 synchronized blocks/CU, staging fully exposed).
// acc[8] + 2 transient uint4 -> ~40 VGPR, safe under the (256,8) 64-VGPR cap.
#define LSTRIDE 12  // u32 per pixel slot (32B data + 16B pad)
__global__ __launch_bounds__(256, 8) void adder_conv_fused(const float* __restrict__ x,
                                                           const uint32_t* __restrict__ qwp,
                                                           float* __restrict__ out) {
    __shared__ __align__(16) uint32_t sx[6 * 18 * LSTRIDE];   // 5184 B
    int tid = threadIdx.x;
    // XCD-contiguous remap: XCD k owns 512 consecutive tiles (2 images).
    int b = ((blockIdx.x & 7) << 9) + (blockIdx.x >> 3);
    int n = b >> 8;                 // image 0..15
    int rem = b & 255;              // tile in image (32 rows x 8 cols)
    int h0 = (rem >> 3) * 4, w0 = (rem & 7) * 16;

    // quantize + pack the 6x18 halo (32 ch -> 8 u32/pixel) into LDS.
    for (int q = tid; q < 864; q += 256) {           // 864 = 108 px * 8 cg
        int cg = q / 108;
        int pixel = q - cg * 108;
        int r = pixel / 18, cc = pixel - r * 18;
        int gh = h0 - 1 + r, gw = w0 - 1 + cc;
        uint32_t pk = 0x80808080u;                   // quantized-zero padding
        if ((unsigned)gh < 128u && (unsigned)gw < 128u) {
            const float* base = x + (((size_t)n * 32 + cg * 4) * 128 + gh) * 128 + gw;
            pk = qbyte(base[0])
               | (qbyte(base[16384]) << 8)
               | (qbyte(base[32768]) << 16)
               | (qbyte(base[49152]) << 24);
        }
        sx[pixel * LSTRIDE + cg] = pk;
    }
    __syncthreads();

    int fg = __builtin_amdgcn_readfirstlane(tid >> 6);  // filter group (wave-uniform)
    int px = tid & 63;
    int r = px >> 4;          // row in tile 0..3
    int c = px & 15;          // col in tile 0..15

    uint32_t acc[8];
    #pragma unroll
    for (int f = 0; f < 8; ++f) acc[f] = 0u;

    int lb = (r * 18 + c) * LSTRIDE;
    #pragma unroll 1
    for (int kh = 0; kh < 3; ++kh) {
        #pragma unroll 1
        for (int kw = 0; kw < 3; ++kw) {
            const uint4* p = (const uint4*)(sx + lb + (kh * 18 + kw) * LSTRIDE);
            uint4 x0 = p[0];
            uint4 x1 = p[1];
            // this tap's 8 filters: 256 B contiguous -> one s_load chunk
            const uint32_t* wt = qwp + ((kh * 3 + kw) * 32 + fg * 8) * 8;
            #pragma unroll
            for (int f = 0; f < 8; ++f) {
                const uint4* wp = (const uint4*)(wt + f * 8);
                uint4 wv0 = wp[0], wv1 = wp[1];
                uint32_t a = acc[f];
                a = sadu8(x0.x, wv0.x, a);
                a = sadu8(x0.y, wv0.y, a);
                a = sadu8(x0.z, wv0.z, a);
                a = sadu8(x0.w, wv0.w, a);
                a = sadu8(x1.x, wv1.x, a);
                a = sadu8(x1.y, wv1.y, a);
                a = sadu8(x1.z, wv1.z, a);
                a = sadu8(x1.w, wv1.w, a);
                acc[f] = a;
            }
        }
    }

    size_t obase = (((size_t)n * 32 + fg * 8) * 16384) + (size_t)(h0 + r) * 128 + (w0 + c);
    #pragma unroll
    for (int f = 0; f < 8; ++f) {
        out[obase + (size_t)f * 16384] = -(float)acc[f] * INPUT_SCALE;
    }
}

extern "C" void kernel_launch(void* const* d_in, const int* in_sizes, int n_in,
                              void* d_out, int out_size, void* d_ws, size_t ws_size,
                              hipStream_t stream) {
    const float* x = (const float*)d_in[0];       // (16,32,128,128)
    const float* w = (const float*)d_in[1];       // (32,32,3,3)
    float* out = (float*)d_out;                   // (16,32,128,128)

    uint32_t* qwp = (uint32_t*)d_ws;              // 9216 B

    quant_weight<<<9, 256, 0, stream>>>(w, qwp);
    adder_conv_fused<<<4096, 256, 0, stream>>>(x, qwp, out);
}